// Round 10
// baseline (780.901 us; speedup 1.0000x reference)
//
#include <hip/hip_runtime.h>
#include <math.h>

#define N_PTS 131072
#define HID 256
#define H2 512
#define H4 1024
#define GRIDW 64
#define K1 384          // 2 * 3 * 64 fourier features
#define TILE 64         // points per block; 2 blocks/CU, skewed, for G/E overlap
#define LN_EPS 1e-5f
#define OMEGA 30.0f

typedef __bf16 b16x8 __attribute__((ext_vector_type(8)));
typedef __bf16 b16x4 __attribute__((ext_vector_type(4)));
typedef float f32x4 __attribute__((ext_vector_type(4)));

// ---- packed-fragment weight workspace (element offsets) ----
// chunks c = otile*NK + ks (NK=K/32), 512 elems: o = otile*16 + (lane&15),
// k = ks*32 + (lane>>4)*8 + j  ->  wave fragment load = contiguous 16 B/lane.
#define OFF_FC 0
#define N_FC   (HID * K1)
#define OFF_W1 (OFF_FC + N_FC)
#define N_W1   (H2 * HID)
#define OFF_W2 (OFF_W1 + N_W1)
#define N_W2   (H2 * H2)
#define OFF_W3 (OFF_W2 + N_W2)
#define OFF_W4 (OFF_W3 + N_W2)
#define N_W4   (H4 * H2)
#define N_TOTAL (OFF_W4 + N_W4)

__global__ void prep_kernel(const float* __restrict__ fc, const float* __restrict__ w1,
                            const float* __restrict__ w2, const float* __restrict__ w3,
                            const float* __restrict__ w4, __bf16* __restrict__ ws) {
  int idx = blockIdx.x * blockDim.x + threadIdx.x;
  if (idx >= N_TOTAL) return;
  int r, K;
  const float* src = nullptr;
  int region;
  if (idx < OFF_W1)      { r = idx - OFF_FC; K = K1;  region = 0; }
  else if (idx < OFF_W2) { r = idx - OFF_W1; K = HID; src = w1; region = 1; }
  else if (idx < OFF_W3) { r = idx - OFF_W2; K = H2;  src = w2; region = 1; }
  else if (idx < OFF_W4) { r = idx - OFF_W3; K = H2;  src = w3; region = 1; }
  else                   { r = idx - OFF_W4; K = H2;  src = w4; region = 1; }
  int NK = K / 32;
  int c = r >> 9, p = r & 511;
  int otile = c / NK, ks = c % NK;
  int lane = p >> 3, j = p & 7;
  int o = otile * 16 + (lane & 15);
  int k = ks * 32 + ((lane >> 4) << 3) + j;
  float v;
  if (region == 0) {
    int s = k / 192, rem = k % 192, i = rem / GRIDW, g = rem % GRIDW;
    v = fc[((s * HID + o) * 3 + i) * GRIDW + g];
  } else {
    v = src[o * K + k];
  }
  ws[idx] = (__bf16)v;
}

// ---------------- fused INR kernel ----------------
// In-place LDS act tile [64 pts][<=512 ch] bf16 (64 KB), swizzle ((n&15)<<4).
// 256 thr / 4 waves, launch_bounds(256,2) -> 2 blocks/CU, 256 regs/wave.
// 512-wide gemms: OT=8/wave, acc[8][4]=128 AGPR; W frags in groups of 4;
// epilogues with unroll<=2 and TRANSIENT weight loads (r9 lesson: a fully
// unrolled OT=8 epilogue hoists 128 regs of wout loads -> spill).
// Odd blocks s_sleep ~3.4us at start: anti-phase the two resident blocks so
// one block's MFMA phase overlaps the other's VALU epilogue.

__device__ __forceinline__ float actfn(float z) {
  const float L2E = 1.4426950408889634f;
  float t2 = __builtin_amdgcn_exp2f((2.0f * OMEGA * L2E) * z);
  float th = 1.0f - 2.0f * __builtin_amdgcn_rcpf(t2 + 1.0f);
  float se = __builtin_amdgcn_exp2f(-L2E * z);
  float sg = __builtin_amdgcn_rcpf(1.0f + se);
  return (z + th) * sg;
}

__device__ __forceinline__ void fast_sincos(float ang, float* s, float* c) {
  const float INV2PI = 0.15915493667125702f;
  float r = __builtin_amdgcn_fractf(ang * INV2PI);
  *s = __builtin_amdgcn_sinf(r);
  *c = __builtin_amdgcn_cosf(r);
}

#define SWZ(n) (((n) & 15) << 4)

// D = W . X^T via mfma(Wfrag, Xfrag): o = (lane>>4)*4+reg (+16*ot),
// n = lane&15 (+16*nt).  W packed-fragment; wf in groups of 4.
template <int K, int OT>
__device__ __forceinline__ void gemm_kloop(const unsigned char* sX, const __bf16* __restrict__ W,
                                           int lane, int o_base, f32x4 (&acc)[OT][4]) {
  const int l15 = lane & 15, lh = lane >> 4;
  constexpr int NK = K / 32;
#pragma unroll 1
  for (int ks = 0; ks < NK; ++ks) {
    b16x8 xf[4];
#pragma unroll
    for (int nt = 0; nt < 4; ++nt) {
      int n = nt * 16 + l15;
      int kb = ks * 64 + (lh << 4);
      xf[nt] = *(const b16x8*)(sX + n * 1024 + (kb ^ SWZ(n)));
    }
#pragma unroll
    for (int g = 0; g < OT / 4; ++g) {
      b16x8 wf[4];
#pragma unroll
      for (int i = 0; i < 4; ++i) {
        int ot = g * 4 + i;
        wf[i] = *(const b16x8*)(W + (size_t)((o_base / 16 + ot) * NK + ks) * 512 + lane * 8);
      }
#pragma unroll
      for (int i = 0; i < 4; ++i)
#pragma unroll
        for (int nt = 0; nt < 4; ++nt)
          acc[g * 4 + i][nt] =
              __builtin_amdgcn_mfma_f32_16x16x32_bf16(wf[i], xf[nt], acc[g * 4 + i][nt], 0, 0, 0);
    }
  }
}

// one sine layer IN PLACE: read sAct (K ch), write sAct (512 ch). 4 waves * OT=8.
template <int K>
__device__ __forceinline__ void sine_layer_ip(unsigned char* sAct,
                                              const __bf16* __restrict__ W,
                                              const float* __restrict__ bias, int lane, int wid) {
  f32x4 acc[8][4] = {};
  const int o_base = wid * 128;
  gemm_kloop<K, 8>(sAct, W, lane, o_base, acc);
  const int l15 = lane & 15, lh = lane >> 4;
  __syncthreads();  // all waves finished READING sAct
#pragma unroll 2
  for (int ot = 0; ot < 8; ++ot) {
    int o0 = o_base + ot * 16 + (lh << 2);
    f32x4 bia = *(const f32x4*)(bias + o0);
#pragma unroll
    for (int nt = 0; nt < 4; ++nt) {
      int n = nt * 16 + l15;
      b16x4 h;
      h[0] = (__bf16)actfn(acc[ot][nt][0] + bia[0]);
      h[1] = (__bf16)actfn(acc[ot][nt][1] + bia[1]);
      h[2] = (__bf16)actfn(acc[ot][nt][2] + bia[2]);
      h[3] = (__bf16)actfn(acc[ot][nt][3] + bia[3]);
      *(b16x4*)(sAct + n * 1024 + ((o0 * 2) ^ SWZ(n))) = h;
    }
  }
  __syncthreads();  // writes visible
}

__global__ __launch_bounds__(256, 2) void fkan_inr_kernel(
    const float* __restrict__ coords, const float* __restrict__ fkan_bias,
    const float* __restrict__ ln_g, const float* __restrict__ ln_b,
    const float* __restrict__ b1, const float* __restrict__ b2,
    const float* __restrict__ b3, const float* __restrict__ b4,
    const float* __restrict__ wout, const float* __restrict__ bout,
    const __bf16* __restrict__ ws, float* __restrict__ out) {
  __shared__ __align__(16) unsigned char sAct[TILE * 1024];   // 64 KB
  __shared__ float sSum[TILE], sSqs[TILE];
  __shared__ float sOutF[TILE][4];

  const int tid = threadIdx.x;
  const int lane = tid & 63, wid = tid >> 6;         // 4 waves
  const int l15 = lane & 15, lh = lane >> 4;
  const int base_n = blockIdx.x * TILE;

  // anti-phase skew: odd blocks start ~3.4us late so the two co-resident
  // blocks' G (MFMA) and E (VALU) phases interleave instead of colliding.
  if (blockIdx.x & 1) __builtin_amdgcn_s_sleep(127);

  // ---- F: fourier features -> sAct[n][k], k<384 ; zero stats + out acc
  if (tid < TILE) {
    sSum[tid] = 0.f; sSqs[tid] = 0.f;
    sOutF[tid][0] = 0.f; sOutF[tid][1] = 0.f; sOutF[tid][2] = 0.f; sOutF[tid][3] = 0.f;
  }
#pragma unroll
  for (int p = 0; p < 6; ++p) {
    int id = tid + p * 256;               // 0..1535 = (n, i, gchunk of 8)
    int n = id / 24, rem = id % 24, i = rem >> 3, g0 = (rem & 7) * 8;
    float c = coords[(base_n + n) * 3 + i];
    b16x8 cv, sv;
#pragma unroll
    for (int j = 0; j < 8; ++j) {
      float ang = c * (float)(g0 + j + 1);
      float s, co;
      fast_sincos(ang, &s, &co);
      cv[j] = (__bf16)co;
      sv[j] = (__bf16)s;
    }
    int kc = (i * GRIDW + g0) * 2;
    *(b16x8*)(sAct + n * 1024 + (kc ^ SWZ(n))) = cv;
    int ks2 = (192 + i * GRIDW + g0) * 2;
    *(b16x8*)(sAct + n * 1024 + (ks2 ^ SWZ(n))) = sv;
  }
  __syncthreads();

  // ---- GEMM1 (384 -> 256) + fkan_bias + LayerNorm, in place. OT=4/wave.
  {
    f32x4 acc[4][4] = {};
    const int o_base = wid * 64;
    gemm_kloop<K1, 4>(sAct, ws + OFF_FC, lane, o_base, acc);
#pragma unroll
    for (int ot = 0; ot < 4; ++ot) {
      int o0 = o_base + ot * 16 + (lh << 2);
      f32x4 bia = *(const f32x4*)(fkan_bias + o0);
#pragma unroll
      for (int nt = 0; nt < 4; ++nt) acc[ot][nt] += bia;
    }
#pragma unroll
    for (int nt = 0; nt < 4; ++nt) {
      float s = 0.f, q = 0.f;
#pragma unroll
      for (int ot = 0; ot < 4; ++ot)
#pragma unroll
        for (int r = 0; r < 4; ++r) { float z = acc[ot][nt][r]; s += z; q += z * z; }
      s += __shfl_xor(s, 16); q += __shfl_xor(q, 16);
      s += __shfl_xor(s, 32); q += __shfl_xor(q, 32);
      if (lane < 16) {
        atomicAdd(&sSum[nt * 16 + lane], s);
        atomicAdd(&sSqs[nt * 16 + lane], q);
      }
    }
    __syncthreads();  // stats ready AND all feature reads done
#pragma unroll
    for (int nt = 0; nt < 4; ++nt) {
      int n = nt * 16 + l15;
      float mu = sSum[n] * (1.f / HID);
      float var = sSqs[n] * (1.f / HID) - mu * mu;
      float rs = rsqrtf(var + LN_EPS);
#pragma unroll
      for (int ot = 0; ot < 4; ++ot) {
        int o0 = o_base + ot * 16 + (lh << 2);
        f32x4 g4 = *(const f32x4*)(ln_g + o0);
        f32x4 bb = *(const f32x4*)(ln_b + o0);
        b16x4 h;
        h[0] = (__bf16)((acc[ot][nt][0] - mu) * rs * g4[0] + bb[0]);
        h[1] = (__bf16)((acc[ot][nt][1] - mu) * rs * g4[1] + bb[1]);
        h[2] = (__bf16)((acc[ot][nt][2] - mu) * rs * g4[2] + bb[2]);
        h[3] = (__bf16)((acc[ot][nt][3] - mu) * rs * g4[3] + bb[3]);
        *(b16x4*)(sAct + n * 1024 + ((o0 * 2) ^ SWZ(n))) = h;
      }
    }
    __syncthreads();
  }

  // ---- sine layers 1..3 (in place)
  sine_layer_ip<HID>(sAct, ws + OFF_W1, b1, lane, wid);
  sine_layer_ip<H2>(sAct, ws + OFF_W2, b2, lane, wid);
  sine_layer_ip<H2>(sAct, ws + OFF_W3, b3, lane, wid);

  // ---- layer 4 (512 -> 1024) fused with output projection (1024 -> 3)
  {
    float pj[4][3] = {};
#pragma unroll 1
    for (int pass = 0; pass < 2; ++pass) {
      f32x4 acc[8][4] = {};
      int o_base = pass * 512 + wid * 128;
      gemm_kloop<H2, 8>(sAct, ws + OFF_W4, lane, o_base, acc);
      // unroll 1: keep wout/b4 loads TRANSIENT (16 regs), not 8x16 hoisted.
#pragma unroll 1
      for (int ot = 0; ot < 8; ++ot) {
        int o0 = o_base + ot * 16 + (lh << 2);
        f32x4 bia = *(const f32x4*)(b4 + o0);
        f32x4 wo0 = *(const f32x4*)(wout + 0 * H4 + o0);
        f32x4 wo1 = *(const f32x4*)(wout + 1 * H4 + o0);
        f32x4 wo2 = *(const f32x4*)(wout + 2 * H4 + o0);
#pragma unroll
        for (int nt = 0; nt < 4; ++nt) {
          float a0 = actfn(acc[ot][nt][0] + bia[0]);
          float a1 = actfn(acc[ot][nt][1] + bia[1]);
          float a2 = actfn(acc[ot][nt][2] + bia[2]);
          float a3 = actfn(acc[ot][nt][3] + bia[3]);
          pj[nt][0] += a0 * wo0[0] + a1 * wo0[1] + a2 * wo0[2] + a3 * wo0[3];
          pj[nt][1] += a0 * wo1[0] + a1 * wo1[1] + a2 * wo1[2] + a3 * wo1[3];
          pj[nt][2] += a0 * wo2[0] + a1 * wo2[1] + a2 * wo2[2] + a3 * wo2[3];
        }
      }
    }
#pragma unroll
    for (int nt = 0; nt < 4; ++nt)
#pragma unroll
      for (int j = 0; j < 3; ++j) {
        float r = pj[nt][j];
        r += __shfl_xor(r, 16);
        r += __shfl_xor(r, 32);
        if (lane < 16) atomicAdd(&sOutF[nt * 16 + lane][j], r);
      }
    __syncthreads();
    if (tid < TILE * 3) {
      int n = tid / 3, j = tid % 3;
      out[(base_n + n) * 3 + j] = sOutF[n][j] + bout[j];
    }
  }
}

extern "C" void kernel_launch(void* const* d_in, const int* in_sizes, int n_in,
                              void* d_out, int out_size, void* d_ws, size_t ws_size,
                              hipStream_t stream) {
  const float* coords    = (const float*)d_in[0];
  const float* fc        = (const float*)d_in[1];
  const float* fkan_bias = (const float*)d_in[2];
  const float* ln_g      = (const float*)d_in[3];
  const float* ln_b      = (const float*)d_in[4];
  const float* w1        = (const float*)d_in[5];
  const float* b1        = (const float*)d_in[6];
  const float* w2        = (const float*)d_in[7];
  const float* b2        = (const float*)d_in[8];
  const float* w3        = (const float*)d_in[9];
  const float* b3        = (const float*)d_in[10];
  const float* w4        = (const float*)d_in[11];
  const float* b4        = (const float*)d_in[12];
  const float* wout      = (const float*)d_in[13];
  const float* bout      = (const float*)d_in[14];
  float* out = (float*)d_out;
  __bf16* ws = (__bf16*)d_ws;

  prep_kernel<<<(N_TOTAL + 255) / 256, 256, 0, stream>>>(fc, w1, w2, w3, w4, ws);
  fkan_inr_kernel<<<N_PTS / TILE, 256, 0, stream>>>(coords, fkan_bias, ln_g, ln_b,
                                                    b1, b2, b3, b4, wout, bout, ws, out);
}

// Round 11
// 699.905 us; speedup vs baseline: 1.1157x; 1.1157x over previous
//
#include <hip/hip_runtime.h>
#include <math.h>

#define N_PTS 131072
#define HID 256
#define H2 512
#define H4 1024
#define GRIDW 64
#define K1 384          // 2 * 3 * 64 fourier features
#define TILE 64         // points per block; 2 blocks/CU, skewed, for G/E overlap
#define LN_EPS 1e-5f
#define OMEGA 30.0f

typedef __bf16 b16x8 __attribute__((ext_vector_type(8)));
typedef __bf16 b16x4 __attribute__((ext_vector_type(4)));
typedef float f32x4 __attribute__((ext_vector_type(4)));

// ---- packed-fragment weight workspace (element offsets) ----
// chunks c = otile*NK + ks (NK=K/32), 512 elems: o = otile*16 + (lane&15),
// k = ks*32 + (lane>>4)*8 + j  ->  wave fragment load = contiguous 16 B/lane.
#define OFF_FC 0
#define N_FC   (HID * K1)
#define OFF_W1 (OFF_FC + N_FC)
#define N_W1   (H2 * HID)
#define OFF_W2 (OFF_W1 + N_W1)
#define N_W2   (H2 * H2)
#define OFF_W3 (OFF_W2 + N_W2)
#define OFF_W4 (OFF_W3 + N_W2)
#define N_W4   (H4 * H2)
#define N_TOTAL (OFF_W4 + N_W4)

__global__ void prep_kernel(const float* __restrict__ fc, const float* __restrict__ w1,
                            const float* __restrict__ w2, const float* __restrict__ w3,
                            const float* __restrict__ w4, __bf16* __restrict__ ws) {
  int idx = blockIdx.x * blockDim.x + threadIdx.x;
  if (idx >= N_TOTAL) return;
  int r, K;
  const float* src = nullptr;
  int region;
  if (idx < OFF_W1)      { r = idx - OFF_FC; K = K1;  region = 0; }
  else if (idx < OFF_W2) { r = idx - OFF_W1; K = HID; src = w1; region = 1; }
  else if (idx < OFF_W3) { r = idx - OFF_W2; K = H2;  src = w2; region = 1; }
  else if (idx < OFF_W4) { r = idx - OFF_W3; K = H2;  src = w3; region = 1; }
  else                   { r = idx - OFF_W4; K = H2;  src = w4; region = 1; }
  int NK = K / 32;
  int c = r >> 9, p = r & 511;
  int otile = c / NK, ks = c % NK;
  int lane = p >> 3, j = p & 7;
  int o = otile * 16 + (lane & 15);
  int k = ks * 32 + ((lane >> 4) << 3) + j;
  float v;
  if (region == 0) {
    int s = k / 192, rem = k % 192, i = rem / GRIDW, g = rem % GRIDW;
    v = fc[((s * HID + o) * 3 + i) * GRIDW + g];
  } else {
    v = src[o * K + k];
  }
  ws[idx] = (__bf16)v;
}

// ---------------- fused INR kernel ----------------
// In-place LDS act tile [64 pts][<=512 ch] bf16 (64 KB), swizzle ((n&15)<<4).
// 256 thr / 4 waves, launch_bounds(256,2) -> 2 blocks/CU, 256 regs/wave.
// 512-wide gemms: OT=8/wave, acc[8][4]=128 AGPR (STATIC indexing only —
// r10 lesson: runtime-indexed acc goes to scratch, 1.3 GB writeback).
// Epilogues fully unrolled + sched_barrier(0) per ot iteration so each
// iteration's weight loads stay transient (r9 lesson: unfenced full unroll
// hoists 160 regs of wout loads -> spill).
// Odd blocks s_sleep ~3.4us: anti-phase the two resident blocks so one
// block's MFMA phase overlaps the other's VALU epilogue.

__device__ __forceinline__ float actfn(float z) {
  const float L2E = 1.4426950408889634f;
  float t2 = __builtin_amdgcn_exp2f((2.0f * OMEGA * L2E) * z);
  float th = 1.0f - 2.0f * __builtin_amdgcn_rcpf(t2 + 1.0f);
  float se = __builtin_amdgcn_exp2f(-L2E * z);
  float sg = __builtin_amdgcn_rcpf(1.0f + se);
  return (z + th) * sg;
}

__device__ __forceinline__ void fast_sincos(float ang, float* s, float* c) {
  const float INV2PI = 0.15915493667125702f;
  float r = __builtin_amdgcn_fractf(ang * INV2PI);
  *s = __builtin_amdgcn_sinf(r);
  *c = __builtin_amdgcn_cosf(r);
}

#define SWZ(n) (((n) & 15) << 4)

// D = W . X^T via mfma(Wfrag, Xfrag): o = (lane>>4)*4+reg (+16*ot),
// n = lane&15 (+16*nt).  W packed-fragment; wf in groups of 4.
template <int K, int OT>
__device__ __forceinline__ void gemm_kloop(const unsigned char* sX, const __bf16* __restrict__ W,
                                           int lane, int o_base, f32x4 (&acc)[OT][4]) {
  const int l15 = lane & 15, lh = lane >> 4;
  constexpr int NK = K / 32;
#pragma unroll 1
  for (int ks = 0; ks < NK; ++ks) {
    b16x8 xf[4];
#pragma unroll
    for (int nt = 0; nt < 4; ++nt) {
      int n = nt * 16 + l15;
      int kb = ks * 64 + (lh << 4);
      xf[nt] = *(const b16x8*)(sX + n * 1024 + (kb ^ SWZ(n)));
    }
#pragma unroll
    for (int g = 0; g < OT / 4; ++g) {
      b16x8 wf[4];
#pragma unroll
      for (int i = 0; i < 4; ++i) {
        int ot = g * 4 + i;
        wf[i] = *(const b16x8*)(W + (size_t)((o_base / 16 + ot) * NK + ks) * 512 + lane * 8);
      }
#pragma unroll
      for (int i = 0; i < 4; ++i)
#pragma unroll
        for (int nt = 0; nt < 4; ++nt)
          acc[g * 4 + i][nt] =
              __builtin_amdgcn_mfma_f32_16x16x32_bf16(wf[i], xf[nt], acc[g * 4 + i][nt], 0, 0, 0);
    }
  }
}

// one sine layer IN PLACE: read sAct (K ch), write sAct (512 ch). 4 waves * OT=8.
// Fully unrolled (static acc idx); sched_barrier(0) fences per-ot loads.
template <int K>
__device__ __forceinline__ void sine_layer_ip(unsigned char* sAct,
                                              const __bf16* __restrict__ W,
                                              const float* __restrict__ bias, int lane, int wid) {
  f32x4 acc[8][4] = {};
  const int o_base = wid * 128;
  gemm_kloop<K, 8>(sAct, W, lane, o_base, acc);
  const int l15 = lane & 15, lh = lane >> 4;
  __syncthreads();  // all waves finished READING sAct
#pragma unroll
  for (int ot = 0; ot < 8; ++ot) {
    __builtin_amdgcn_sched_barrier(0);   // keep this ot's loads transient
    int o0 = o_base + ot * 16 + (lh << 2);
    f32x4 bia = *(const f32x4*)(bias + o0);
#pragma unroll
    for (int nt = 0; nt < 4; ++nt) {
      int n = nt * 16 + l15;
      b16x4 h;
      h[0] = (__bf16)actfn(acc[ot][nt][0] + bia[0]);
      h[1] = (__bf16)actfn(acc[ot][nt][1] + bia[1]);
      h[2] = (__bf16)actfn(acc[ot][nt][2] + bia[2]);
      h[3] = (__bf16)actfn(acc[ot][nt][3] + bia[3]);
      *(b16x4*)(sAct + n * 1024 + ((o0 * 2) ^ SWZ(n))) = h;
    }
  }
  __syncthreads();  // writes visible
}

__global__ __launch_bounds__(256, 2) void fkan_inr_kernel(
    const float* __restrict__ coords, const float* __restrict__ fkan_bias,
    const float* __restrict__ ln_g, const float* __restrict__ ln_b,
    const float* __restrict__ b1, const float* __restrict__ b2,
    const float* __restrict__ b3, const float* __restrict__ b4,
    const float* __restrict__ wout, const float* __restrict__ bout,
    const __bf16* __restrict__ ws, float* __restrict__ out) {
  __shared__ __align__(16) unsigned char sAct[TILE * 1024];   // 64 KB
  __shared__ float sSum[TILE], sSqs[TILE];
  __shared__ float sOutF[TILE][4];

  const int tid = threadIdx.x;
  const int lane = tid & 63, wid = tid >> 6;         // 4 waves
  const int l15 = lane & 15, lh = lane >> 4;
  const int base_n = blockIdx.x * TILE;

  // anti-phase skew: odd blocks start ~3.4us late so the two co-resident
  // blocks' G (MFMA) and E (VALU) phases interleave instead of colliding.
  if (blockIdx.x & 1) __builtin_amdgcn_s_sleep(127);

  // ---- F: fourier features -> sAct[n][k], k<384 ; zero stats + out acc
  if (tid < TILE) {
    sSum[tid] = 0.f; sSqs[tid] = 0.f;
    sOutF[tid][0] = 0.f; sOutF[tid][1] = 0.f; sOutF[tid][2] = 0.f; sOutF[tid][3] = 0.f;
  }
#pragma unroll
  for (int p = 0; p < 6; ++p) {
    int id = tid + p * 256;               // 0..1535 = (n, i, gchunk of 8)
    int n = id / 24, rem = id % 24, i = rem >> 3, g0 = (rem & 7) * 8;
    float c = coords[(base_n + n) * 3 + i];
    b16x8 cv, sv;
#pragma unroll
    for (int j = 0; j < 8; ++j) {
      float ang = c * (float)(g0 + j + 1);
      float s, co;
      fast_sincos(ang, &s, &co);
      cv[j] = (__bf16)co;
      sv[j] = (__bf16)s;
    }
    int kc = (i * GRIDW + g0) * 2;
    *(b16x8*)(sAct + n * 1024 + (kc ^ SWZ(n))) = cv;
    int ks2 = (192 + i * GRIDW + g0) * 2;
    *(b16x8*)(sAct + n * 1024 + (ks2 ^ SWZ(n))) = sv;
  }
  __syncthreads();

  // ---- GEMM1 (384 -> 256) + fkan_bias + LayerNorm, in place. OT=4/wave.
  {
    f32x4 acc[4][4] = {};
    const int o_base = wid * 64;
    gemm_kloop<K1, 4>(sAct, ws + OFF_FC, lane, o_base, acc);
#pragma unroll
    for (int ot = 0; ot < 4; ++ot) {
      int o0 = o_base + ot * 16 + (lh << 2);
      f32x4 bia = *(const f32x4*)(fkan_bias + o0);
#pragma unroll
      for (int nt = 0; nt < 4; ++nt) acc[ot][nt] += bia;
    }
#pragma unroll
    for (int nt = 0; nt < 4; ++nt) {
      float s = 0.f, q = 0.f;
#pragma unroll
      for (int ot = 0; ot < 4; ++ot)
#pragma unroll
        for (int r = 0; r < 4; ++r) { float z = acc[ot][nt][r]; s += z; q += z * z; }
      s += __shfl_xor(s, 16); q += __shfl_xor(q, 16);
      s += __shfl_xor(s, 32); q += __shfl_xor(q, 32);
      if (lane < 16) {
        atomicAdd(&sSum[nt * 16 + lane], s);
        atomicAdd(&sSqs[nt * 16 + lane], q);
      }
    }
    __syncthreads();  // stats ready AND all feature reads done
#pragma unroll
    for (int nt = 0; nt < 4; ++nt) {
      __builtin_amdgcn_sched_barrier(0);
      int n = nt * 16 + l15;
      float mu = sSum[n] * (1.f / HID);
      float var = sSqs[n] * (1.f / HID) - mu * mu;
      float rs = rsqrtf(var + LN_EPS);
#pragma unroll
      for (int ot = 0; ot < 4; ++ot) {
        int o0 = o_base + ot * 16 + (lh << 2);
        f32x4 g4 = *(const f32x4*)(ln_g + o0);
        f32x4 bb = *(const f32x4*)(ln_b + o0);
        b16x4 h;
        h[0] = (__bf16)((acc[ot][nt][0] - mu) * rs * g4[0] + bb[0]);
        h[1] = (__bf16)((acc[ot][nt][1] - mu) * rs * g4[1] + bb[1]);
        h[2] = (__bf16)((acc[ot][nt][2] - mu) * rs * g4[2] + bb[2]);
        h[3] = (__bf16)((acc[ot][nt][3] - mu) * rs * g4[3] + bb[3]);
        *(b16x4*)(sAct + n * 1024 + ((o0 * 2) ^ SWZ(n))) = h;
      }
    }
    __syncthreads();
  }

  // ---- sine layers 1..3 (in place)
  sine_layer_ip<HID>(sAct, ws + OFF_W1, b1, lane, wid);
  sine_layer_ip<H2>(sAct, ws + OFF_W2, b2, lane, wid);
  sine_layer_ip<H2>(sAct, ws + OFF_W3, b3, lane, wid);

  // ---- layer 4 (512 -> 1024) fused with output projection (1024 -> 3)
  {
    float pj[4][3] = {};
#pragma unroll 1
    for (int pass = 0; pass < 2; ++pass) {
      f32x4 acc[8][4] = {};
      int o_base = pass * 512 + wid * 128;
      gemm_kloop<H2, 8>(sAct, ws + OFF_W4, lane, o_base, acc);
      // fully unrolled (static acc idx); sched_barrier stops wout hoisting.
#pragma unroll
      for (int ot = 0; ot < 8; ++ot) {
        __builtin_amdgcn_sched_barrier(0);
        int o0 = o_base + ot * 16 + (lh << 2);
        f32x4 bia = *(const f32x4*)(b4 + o0);
        f32x4 wo0 = *(const f32x4*)(wout + 0 * H4 + o0);
        f32x4 wo1 = *(const f32x4*)(wout + 1 * H4 + o0);
        f32x4 wo2 = *(const f32x4*)(wout + 2 * H4 + o0);
#pragma unroll
        for (int nt = 0; nt < 4; ++nt) {
          float a0 = actfn(acc[ot][nt][0] + bia[0]);
          float a1 = actfn(acc[ot][nt][1] + bia[1]);
          float a2 = actfn(acc[ot][nt][2] + bia[2]);
          float a3 = actfn(acc[ot][nt][3] + bia[3]);
          pj[nt][0] += a0 * wo0[0] + a1 * wo0[1] + a2 * wo0[2] + a3 * wo0[3];
          pj[nt][1] += a0 * wo1[0] + a1 * wo1[1] + a2 * wo1[2] + a3 * wo1[3];
          pj[nt][2] += a0 * wo2[0] + a1 * wo2[1] + a2 * wo2[2] + a3 * wo2[3];
        }
      }
    }
#pragma unroll
    for (int nt = 0; nt < 4; ++nt)
#pragma unroll
      for (int j = 0; j < 3; ++j) {
        float r = pj[nt][j];
        r += __shfl_xor(r, 16);
        r += __shfl_xor(r, 32);
        if (lane < 16) atomicAdd(&sOutF[nt * 16 + lane][j], r);
      }
    __syncthreads();
    if (tid < TILE * 3) {
      int n = tid / 3, j = tid % 3;
      out[(base_n + n) * 3 + j] = sOutF[n][j] + bout[j];
    }
  }
}

extern "C" void kernel_launch(void* const* d_in, const int* in_sizes, int n_in,
                              void* d_out, int out_size, void* d_ws, size_t ws_size,
                              hipStream_t stream) {
  const float* coords    = (const float*)d_in[0];
  const float* fc        = (const float*)d_in[1];
  const float* fkan_bias = (const float*)d_in[2];
  const float* ln_g      = (const float*)d_in[3];
  const float* ln_b      = (const float*)d_in[4];
  const float* w1        = (const float*)d_in[5];
  const float* b1        = (const float*)d_in[6];
  const float* w2        = (const float*)d_in[7];
  const float* b2        = (const float*)d_in[8];
  const float* w3        = (const float*)d_in[9];
  const float* b3        = (const float*)d_in[10];
  const float* w4        = (const float*)d_in[11];
  const float* b4        = (const float*)d_in[12];
  const float* wout      = (const float*)d_in[13];
  const float* bout      = (const float*)d_in[14];
  float* out = (float*)d_out;
  __bf16* ws = (__bf16*)d_ws;

  prep_kernel<<<(N_TOTAL + 255) / 256, 256, 0, stream>>>(fc, w1, w2, w3, w4, ws);
  fkan_inr_kernel<<<N_PTS / TILE, 256, 0, stream>>>(coords, fkan_bias, ln_g, ln_b,
                                                    b1, b2, b3, b4, wout, bout, ws, out);
}

// Round 13
// 444.169 us; speedup vs baseline: 1.7581x; 1.5758x over previous
//
#include <hip/hip_runtime.h>
#include <math.h>

#define N_PTS 131072
#define HID 256
#define H2 512
#define H4 1024
#define GRIDW 64
#define K1 384          // 2 * 3 * 64 fourier features
#define TILE 64         // points per block; 2 blocks/CU, skewed, cross-block G/E overlap
#define LN_EPS 1e-5f
#define OMEGA 30.0f

typedef __bf16 b16x8 __attribute__((ext_vector_type(8)));
typedef __bf16 b16x4 __attribute__((ext_vector_type(4)));
typedef float f32x4 __attribute__((ext_vector_type(4)));

// ---- packed-fragment weight workspace (element offsets), 16x16x32 MFMA ----
// chunks c = otile*NK + ks (NK=K/32), 512 elems: o = otile*16 + (lane&15),
// k = ks*32 + (lane>>4)*8 + j  ->  wave fragment load = contiguous 16 B/lane.
#define OFF_FC 0
#define N_FC   (HID * K1)
#define OFF_W1 (OFF_FC + N_FC)
#define N_W1   (H2 * HID)
#define OFF_W2 (OFF_W1 + N_W1)
#define N_W2   (H2 * H2)
#define OFF_W3 (OFF_W2 + N_W2)
#define OFF_W4 (OFF_W3 + N_W2)
#define N_W4   (H4 * H2)
#define N_TOTAL (OFF_W4 + N_W4)

__global__ void prep_kernel(const float* __restrict__ fc, const float* __restrict__ w1,
                            const float* __restrict__ w2, const float* __restrict__ w3,
                            const float* __restrict__ w4, __bf16* __restrict__ ws) {
  int idx = blockIdx.x * blockDim.x + threadIdx.x;
  if (idx >= N_TOTAL) return;
  int r, K;
  const float* src = nullptr;
  int region;
  if (idx < OFF_W1)      { r = idx - OFF_FC; K = K1;  region = 0; }
  else if (idx < OFF_W2) { r = idx - OFF_W1; K = HID; src = w1; region = 1; }
  else if (idx < OFF_W3) { r = idx - OFF_W2; K = H2;  src = w2; region = 1; }
  else if (idx < OFF_W4) { r = idx - OFF_W3; K = H2;  src = w3; region = 1; }
  else                   { r = idx - OFF_W4; K = H2;  src = w4; region = 1; }
  int NK = K / 32;
  int c = r >> 9, p = r & 511;
  int otile = c / NK, ks = c % NK;
  int lane = p >> 3, j = p & 7;
  int o = otile * 16 + (lane & 15);
  int k = ks * 32 + ((lane >> 4) << 3) + j;
  float v;
  if (region == 0) {
    int s = k / 192, rem = k % 192, i = rem / GRIDW, g = rem % GRIDW;
    v = fc[((s * HID + o) * 3 + i) * GRIDW + g];
  } else {
    v = src[o * K + k];
  }
  ws[idx] = (__bf16)v;
}

// ---------------- fused INR kernel ----------------
// r9 skeleton (PASSED correctness): TILE=64 in-place LDS tile (64 KB),
// swizzle ((n&15)<<4), 256 thr / 4 waves, launch_bounds(256,2) -> 2 blocks/CU.
// NEW: every 512-wide layer = TWO OT=4 o-passes (acc[4][4] = 64 AGPR each;
// r9's OT=8 single-pass = 128 AGPR + >=128 arch = spill).  Register ledger at
// peak (pass1): acc1 64 AGPR + stash0 16 + xf[4] 32 + wf[4] 32 + addr ~25
// ~= 200 of 256 -> ~55 slack.  All acc/stash indexing compile-time static
// (rule 20).  Cross-block overlap: independent barrier domains + odd-block
// s_sleep skew (~3.4us ~ one G-phase) so block A's MFMA overlaps block B's
// VALU epilogue on the shared SIMDs.

__device__ __forceinline__ float actfn(float z) {
  const float L2E = 1.4426950408889634f;
  float t2 = __builtin_amdgcn_exp2f((2.0f * OMEGA * L2E) * z);
  float th = 1.0f - 2.0f * __builtin_amdgcn_rcpf(t2 + 1.0f);
  float se = __builtin_amdgcn_exp2f(-L2E * z);
  float sg = __builtin_amdgcn_rcpf(1.0f + se);
  return (z + th) * sg;
}

__device__ __forceinline__ void fast_sincos(float ang, float* s, float* c) {
  const float INV2PI = 0.15915493667125702f;
  float r = __builtin_amdgcn_fractf(ang * INV2PI);
  *s = __builtin_amdgcn_sinf(r);
  *c = __builtin_amdgcn_cosf(r);
}

#define SWZ(n) (((n) & 15) << 4)

// D = W . X^T via mfma(Wfrag, Xfrag): o = (lane>>4)*4+reg (+16*ot),
// n = lane&15 (+16*nt).  W packed-fragment.  OT=4 everywhere.
template <int K>
__device__ __forceinline__ void gemm_kloop(const unsigned char* sX, const __bf16* __restrict__ W,
                                           int lane, int o_base, f32x4 (&acc)[4][4]) {
  const int l15 = lane & 15, lh = lane >> 4;
  constexpr int NK = K / 32;
#pragma unroll 1
  for (int ks = 0; ks < NK; ++ks) {
    b16x8 xf[4];
#pragma unroll
    for (int nt = 0; nt < 4; ++nt) {
      int n = nt * 16 + l15;
      int kb = ks * 64 + (lh << 4);
      xf[nt] = *(const b16x8*)(sX + n * 1024 + (kb ^ SWZ(n)));
    }
    b16x8 wf[4];
#pragma unroll
    for (int i = 0; i < 4; ++i)
      wf[i] = *(const b16x8*)(W + (size_t)((o_base / 16 + i) * NK + ks) * 512 + lane * 8);
#pragma unroll
    for (int i = 0; i < 4; ++i)
#pragma unroll
      for (int nt = 0; nt < 4; ++nt)
        acc[i][nt] = __builtin_amdgcn_mfma_f32_16x16x32_bf16(wf[i], xf[nt], acc[i][nt], 0, 0, 0);
  }
}

// one 512-out sine layer IN PLACE, two OT=4 o-passes with bf16 stash.
// pass0: o [wid*64, +64); pass1: o [256 + wid*64, +64).
template <int K>
__device__ __forceinline__ void sine_layer_2p(unsigned char* sAct,
                                              const __bf16* __restrict__ W,
                                              const float* __restrict__ bias, int lane, int wid) {
  const int l15 = lane & 15, lh = lane >> 4;
  const int ob0 = wid * 64, ob1 = 256 + wid * 64;

  f32x4 acc0[4][4] = {};
  gemm_kloop<K>(sAct, W, lane, ob0, acc0);

  b16x4 st0[4][4];                       // 16 VGPR bf16 stash; acc0 dies here
#pragma unroll
  for (int ot = 0; ot < 4; ++ot) {
    int o0 = ob0 + ot * 16 + (lh << 2);
    f32x4 bia = *(const f32x4*)(bias + o0);
#pragma unroll
    for (int nt = 0; nt < 4; ++nt) {
      st0[ot][nt][0] = (__bf16)actfn(acc0[ot][nt][0] + bia[0]);
      st0[ot][nt][1] = (__bf16)actfn(acc0[ot][nt][1] + bia[1]);
      st0[ot][nt][2] = (__bf16)actfn(acc0[ot][nt][2] + bia[2]);
      st0[ot][nt][3] = (__bf16)actfn(acc0[ot][nt][3] + bia[3]);
    }
  }

  f32x4 acc1[4][4] = {};
  gemm_kloop<K>(sAct, W, lane, ob1, acc1);

  __syncthreads();  // all waves finished READING sAct (both passes)

#pragma unroll
  for (int ot = 0; ot < 4; ++ot) {
    int o0 = ob0 + ot * 16 + (lh << 2);
#pragma unroll
    for (int nt = 0; nt < 4; ++nt) {
      int n = nt * 16 + l15;
      *(b16x4*)(sAct + n * 1024 + ((o0 * 2) ^ SWZ(n))) = st0[ot][nt];
    }
  }
#pragma unroll
  for (int ot = 0; ot < 4; ++ot) {
    int o0 = ob1 + ot * 16 + (lh << 2);
    f32x4 bia = *(const f32x4*)(bias + o0);
#pragma unroll
    for (int nt = 0; nt < 4; ++nt) {
      int n = nt * 16 + l15;
      b16x4 h;
      h[0] = (__bf16)actfn(acc1[ot][nt][0] + bia[0]);
      h[1] = (__bf16)actfn(acc1[ot][nt][1] + bia[1]);
      h[2] = (__bf16)actfn(acc1[ot][nt][2] + bia[2]);
      h[3] = (__bf16)actfn(acc1[ot][nt][3] + bia[3]);
      *(b16x4*)(sAct + n * 1024 + ((o0 * 2) ^ SWZ(n))) = h;
    }
  }
  __syncthreads();  // writes visible
}

__global__ __launch_bounds__(256, 2) void fkan_inr_kernel(
    const float* __restrict__ coords, const float* __restrict__ fkan_bias,
    const float* __restrict__ ln_g, const float* __restrict__ ln_b,
    const float* __restrict__ b1, const float* __restrict__ b2,
    const float* __restrict__ b3, const float* __restrict__ b4,
    const float* __restrict__ wout, const float* __restrict__ bout,
    const __bf16* __restrict__ ws, float* __restrict__ out) {
  __shared__ __align__(16) unsigned char sAct[TILE * 1024];   // 64 KB
  __shared__ float sSum[TILE], sSqs[TILE];
  __shared__ float sOutF[TILE][4];

  const int tid = threadIdx.x;
  const int lane = tid & 63, wid = tid >> 6;         // 4 waves
  const int l15 = lane & 15, lh = lane >> 4;
  const int base_n = blockIdx.x * TILE;

  // anti-phase skew: odd blocks start ~3.4us late so co-resident blocks'
  // G (MFMA) and E (VALU) phases interleave instead of running lockstep.
  if (blockIdx.x & 1) __builtin_amdgcn_s_sleep(127);

  // ---- F: fourier features -> sAct[n][k], k<384 ; zero stats + out acc
  if (tid < TILE) {
    sSum[tid] = 0.f; sSqs[tid] = 0.f;
    sOutF[tid][0] = 0.f; sOutF[tid][1] = 0.f; sOutF[tid][2] = 0.f; sOutF[tid][3] = 0.f;
  }
#pragma unroll
  for (int p = 0; p < 6; ++p) {
    int id = tid + p * 256;               // 0..1535 = (n, i, gchunk of 8)
    int n = id / 24, rem = id % 24, i = rem >> 3, g0 = (rem & 7) * 8;
    float c = coords[(base_n + n) * 3 + i];
    b16x8 cv, sv;
#pragma unroll
    for (int j = 0; j < 8; ++j) {
      float ang = c * (float)(g0 + j + 1);
      float s, co;
      fast_sincos(ang, &s, &co);
      cv[j] = (__bf16)co;
      sv[j] = (__bf16)s;
    }
    int kc = (i * GRIDW + g0) * 2;
    *(b16x8*)(sAct + n * 1024 + (kc ^ SWZ(n))) = cv;
    int ks2 = (192 + i * GRIDW + g0) * 2;
    *(b16x8*)(sAct + n * 1024 + (ks2 ^ SWZ(n))) = sv;
  }
  __syncthreads();

  // ---- GEMM1 (384 -> 256) + fkan_bias + LayerNorm, in place. OT=4/wave.
  {
    f32x4 acc[4][4] = {};
    const int o_base = wid * 64;
    gemm_kloop<K1>(sAct, ws + OFF_FC, lane, o_base, acc);
#pragma unroll
    for (int ot = 0; ot < 4; ++ot) {
      int o0 = o_base + ot * 16 + (lh << 2);
      f32x4 bia = *(const f32x4*)(fkan_bias + o0);
#pragma unroll
      for (int nt = 0; nt < 4; ++nt) acc[ot][nt] += bia;
    }
#pragma unroll
    for (int nt = 0; nt < 4; ++nt) {
      float s = 0.f, q = 0.f;
#pragma unroll
      for (int ot = 0; ot < 4; ++ot)
#pragma unroll
        for (int r = 0; r < 4; ++r) { float z = acc[ot][nt][r]; s += z; q += z * z; }
      s += __shfl_xor(s, 16); q += __shfl_xor(q, 16);
      s += __shfl_xor(s, 32); q += __shfl_xor(q, 32);
      if (lane < 16) {
        atomicAdd(&sSum[nt * 16 + lane], s);
        atomicAdd(&sSqs[nt * 16 + lane], q);
      }
    }
    __syncthreads();  // stats ready AND all feature reads done
#pragma unroll
    for (int nt = 0; nt < 4; ++nt) {
      int n = nt * 16 + l15;
      float mu = sSum[n] * (1.f / HID);
      float var = sSqs[n] * (1.f / HID) - mu * mu;
      float rs = rsqrtf(var + LN_EPS);
#pragma unroll
      for (int ot = 0; ot < 4; ++ot) {
        int o0 = o_base + ot * 16 + (lh << 2);
        f32x4 g4 = *(const f32x4*)(ln_g + o0);
        f32x4 bb = *(const f32x4*)(ln_b + o0);
        b16x4 h;
        h[0] = (__bf16)((acc[ot][nt][0] - mu) * rs * g4[0] + bb[0]);
        h[1] = (__bf16)((acc[ot][nt][1] - mu) * rs * g4[1] + bb[1]);
        h[2] = (__bf16)((acc[ot][nt][2] - mu) * rs * g4[2] + bb[2]);
        h[3] = (__bf16)((acc[ot][nt][3] - mu) * rs * g4[3] + bb[3]);
        *(b16x4*)(sAct + n * 1024 + ((o0 * 2) ^ SWZ(n))) = h;
      }
    }
    __syncthreads();
  }

  // ---- sine layers 1..3 (in place, two OT=4 passes each)
  sine_layer_2p<HID>(sAct, ws + OFF_W1, b1, lane, wid);
  sine_layer_2p<H2>(sAct, ws + OFF_W2, b2, lane, wid);
  sine_layer_2p<H2>(sAct, ws + OFF_W3, b3, lane, wid);

  // ---- layer 4 (512 -> 1024) fused with output projection (1024 -> 3)
  // 4 passes of OT=4 (r7-proven epilogue width; acc 64 AGPR per pass).
  {
    float pj[4][3] = {};
#pragma unroll 1
    for (int pass = 0; pass < 4; ++pass) {
      f32x4 acc[4][4] = {};
      int o_base = pass * 256 + wid * 64;
      gemm_kloop<H2>(sAct, ws + OFF_W4, lane, o_base, acc);
#pragma unroll
      for (int ot = 0; ot < 4; ++ot) {
        int o0 = o_base + ot * 16 + (lh << 2);
        f32x4 bia = *(const f32x4*)(b4 + o0);
        f32x4 wo0 = *(const f32x4*)(wout + 0 * H4 + o0);
        f32x4 wo1 = *(const f32x4*)(wout + 1 * H4 + o0);
        f32x4 wo2 = *(const f32x4*)(wout + 2 * H4 + o0);
#pragma unroll
        for (int nt = 0; nt < 4; ++nt) {
          float a0 = actfn(acc[ot][nt][0] + bia[0]);
          float a1 = actfn(acc[ot][nt][1] + bia[1]);
          float a2 = actfn(acc[ot][nt][2] + bia[2]);
          float a3 = actfn(acc[ot][nt][3] + bia[3]);
          pj[nt][0] += a0 * wo0[0] + a1 * wo0[1] + a2 * wo0[2] + a3 * wo0[3];
          pj[nt][1] += a0 * wo1[0] + a1 * wo1[1] + a2 * wo1[2] + a3 * wo1[3];
          pj[nt][2] += a0 * wo2[0] + a1 * wo2[1] + a2 * wo2[2] + a3 * wo2[3];
        }
      }
    }
#pragma unroll
    for (int nt = 0; nt < 4; ++nt)
#pragma unroll
      for (int j = 0; j < 3; ++j) {
        float r = pj[nt][j];
        r += __shfl_xor(r, 16);
        r += __shfl_xor(r, 32);
        if (lane < 16) atomicAdd(&sOutF[nt * 16 + lane][j], r);
      }
    __syncthreads();
    if (tid < TILE * 3) {
      int n = tid / 3, j = tid % 3;
      out[(base_n + n) * 3 + j] = sOutF[n][j] + bout[j];
    }
  }
}

extern "C" void kernel_launch(void* const* d_in, const int* in_sizes, int n_in,
                              void* d_out, int out_size, void* d_ws, size_t ws_size,
                              hipStream_t stream) {
  const float* coords    = (const float*)d_in[0];
  const float* fc        = (const float*)d_in[1];
  const float* fkan_bias = (const float*)d_in[2];
  const float* ln_g      = (const float*)d_in[3];
  const float* ln_b      = (const float*)d_in[4];
  const float* w1        = (const float*)d_in[5];
  const float* b1        = (const float*)d_in[6];
  const float* w2        = (const float*)d_in[7];
  const float* b2        = (const float*)d_in[8];
  const float* w3        = (const float*)d_in[9];
  const float* b3        = (const float*)d_in[10];
  const float* w4        = (const float*)d_in[11];
  const float* b4        = (const float*)d_in[12];
  const float* wout      = (const float*)d_in[13];
  const float* bout      = (const float*)d_in[14];
  float* out = (float*)d_out;
  __bf16* ws = (__bf16*)d_ws;

  prep_kernel<<<(N_TOTAL + 255) / 256, 256, 0, stream>>>(fc, w1, w2, w3, w4, ws);
  fkan_inr_kernel<<<N_PTS / TILE, 256, 0, stream>>>(coords, fkan_bias, ln_g, ln_b,
                                                    b1, b2, b3, b4, wout, bout, ws, out);
}

// Round 14
// 393.984 us; speedup vs baseline: 1.9821x; 1.1274x over previous
//
#include <hip/hip_runtime.h>
#include <math.h>

#define N_PTS 131072
#define HID 256
#define H2 512
#define H4 1024
#define GRIDW 64
#define K1 384          // 2 * 3 * 64 fourier features
#define TILE 128        // points per block; 1 block/CU (r7 structure, best verified)
#define LN_EPS 1e-5f
#define OMEGA 30.0f

typedef __bf16 b16x8 __attribute__((ext_vector_type(8)));
typedef __bf16 b16x4 __attribute__((ext_vector_type(4)));
typedef float f32x4 __attribute__((ext_vector_type(4)));

// ---- packed-fragment weight workspace (element offsets), 16x16x32 MFMA ----
// chunks c = otile*NK + ks (NK=K/32), 512 elems: o = otile*16 + (lane&15),
// k = ks*32 + (lane>>4)*8 + j  ->  wave fragment load = contiguous 16 B/lane.
#define OFF_FC 0
#define N_FC   (HID * K1)
#define OFF_W1 (OFF_FC + N_FC)
#define N_W1   (H2 * HID)
#define OFF_W2 (OFF_W1 + N_W1)
#define N_W2   (H2 * H2)
#define OFF_W3 (OFF_W2 + N_W2)
#define OFF_W4 (OFF_W3 + N_W2)
#define N_W4   (H4 * H2)
#define N_TOTAL (OFF_W4 + N_W4)

__global__ void prep_kernel(const float* __restrict__ fc, const float* __restrict__ w1,
                            const float* __restrict__ w2, const float* __restrict__ w3,
                            const float* __restrict__ w4, __bf16* __restrict__ ws) {
  int idx = blockIdx.x * blockDim.x + threadIdx.x;
  if (idx >= N_TOTAL) return;
  int r, K;
  const float* src = nullptr;
  int region;
  if (idx < OFF_W1)      { r = idx - OFF_FC; K = K1;  region = 0; }
  else if (idx < OFF_W2) { r = idx - OFF_W1; K = HID; src = w1; region = 1; }
  else if (idx < OFF_W3) { r = idx - OFF_W2; K = H2;  src = w2; region = 1; }
  else if (idx < OFF_W4) { r = idx - OFF_W3; K = H2;  src = w3; region = 1; }
  else                   { r = idx - OFF_W4; K = H2;  src = w4; region = 1; }
  int NK = K / 32;
  int c = r >> 9, p = r & 511;
  int otile = c / NK, ks = c % NK;
  int lane = p >> 3, j = p & 7;
  int o = otile * 16 + (lane & 15);
  int k = ks * 32 + ((lane >> 4) << 3) + j;
  float v;
  if (region == 0) {
    int s = k / 192, rem = k % 192, i = rem / GRIDW, g = rem % GRIDW;
    v = fc[((s * HID + o) * 3 + i) * GRIDW + g];
  } else {
    v = src[o * K + k];
  }
  ws[idx] = (__bf16)v;
}

// ---------------- fused INR kernel ----------------
// r7 structure (best verified, no spill): 1 block/CU, 512 thr / 8 waves,
// launch_bounds(512,2) -> 256 unified regs/wave.  In-place LDS act tile
// [128 pts][<=512 ch] bf16 (128 KB), swizzle ((n&15)<<4).
// r14 change: sine layers compute actfn into a 32-VGPR bf16 stash BEFORE the
// barrier (from acc/AGPRs), so a wave whose gemm drains early runs its E
// (VALU/trans) while the sibling wave on the SIMD still issues MFMAs —
// recovers the G-tail that r7 wasted waiting at the barrier.  Ledger:
// acc 128 AGPR + stash 32 + misc ~40 = ~200 of 256 (no spill expected).

__device__ __forceinline__ float actfn(float z) {
  const float L2E = 1.4426950408889634f;
  float t2 = __builtin_amdgcn_exp2f((2.0f * OMEGA * L2E) * z);
  float th = 1.0f - 2.0f * __builtin_amdgcn_rcpf(t2 + 1.0f);
  float se = __builtin_amdgcn_exp2f(-L2E * z);
  float sg = __builtin_amdgcn_rcpf(1.0f + se);
  return (z + th) * sg;
}

__device__ __forceinline__ void fast_sincos(float ang, float* s, float* c) {
  const float INV2PI = 0.15915493667125702f;
  float r = __builtin_amdgcn_fractf(ang * INV2PI);
  *s = __builtin_amdgcn_sinf(r);
  *c = __builtin_amdgcn_cosf(r);
}

#define SWZ(n) (((n) & 15) << 4)

// D = W . X^T via mfma(Wfrag, Xfrag): o = (lane>>4)*4+reg (+16*ot),
// n = lane&15 (+16*nt).  W packed-fragment.
template <int K, int OT>
__device__ __forceinline__ void gemm_kloop(const unsigned char* sX, const __bf16* __restrict__ W,
                                           int lane, int o_base, f32x4 (&acc)[OT][8]) {
  const int l15 = lane & 15, lh = lane >> 4;
  constexpr int NK = K / 32;
#pragma unroll 1
  for (int ks = 0; ks < NK; ++ks) {
    b16x8 xf[8];
#pragma unroll
    for (int nt = 0; nt < 8; ++nt) {
      int n = nt * 16 + l15;
      int kb = ks * 64 + (lh << 4);
      xf[nt] = *(const b16x8*)(sX + n * 1024 + (kb ^ SWZ(n)));
    }
    b16x8 wf[OT];
#pragma unroll
    for (int ot = 0; ot < OT; ++ot) {
      int chunk = (o_base / 16 + ot) * NK + ks;
      wf[ot] = *(const b16x8*)(W + (size_t)chunk * 512 + lane * 8);
    }
#pragma unroll
    for (int ot = 0; ot < OT; ++ot)
#pragma unroll
      for (int nt = 0; nt < 8; ++nt)
        acc[ot][nt] = __builtin_amdgcn_mfma_f32_16x16x32_bf16(wf[ot], xf[nt], acc[ot][nt], 0, 0, 0);
  }
}

// one sine layer IN PLACE: read sAct (K ch), write sAct (512 ch). 8 waves * OT=4.
// actfn BEFORE the barrier into a bf16 stash (32 VGPR); only LDS writes after.
template <int K>
__device__ __forceinline__ void sine_layer_ip(unsigned char* sAct,
                                              const __bf16* __restrict__ W,
                                              const float* __restrict__ bias, int lane, int wid) {
  f32x4 acc[4][8] = {};
  const int o_base = wid * 64;
  gemm_kloop<K, 4>(sAct, W, lane, o_base, acc);
  const int l15 = lane & 15, lh = lane >> 4;
  b16x4 st[4][8];                        // 32 VGPR bf16 stash; acc dies here
#pragma unroll
  for (int ot = 0; ot < 4; ++ot) {
    int o0 = o_base + ot * 16 + (lh << 2);
    f32x4 bia = *(const f32x4*)(bias + o0);
#pragma unroll
    for (int nt = 0; nt < 8; ++nt) {
      st[ot][nt][0] = (__bf16)actfn(acc[ot][nt][0] + bia[0]);
      st[ot][nt][1] = (__bf16)actfn(acc[ot][nt][1] + bia[1]);
      st[ot][nt][2] = (__bf16)actfn(acc[ot][nt][2] + bia[2]);
      st[ot][nt][3] = (__bf16)actfn(acc[ot][nt][3] + bia[3]);
    }
  }
  __syncthreads();  // all waves finished READING sAct
#pragma unroll
  for (int ot = 0; ot < 4; ++ot) {
    int o0 = o_base + ot * 16 + (lh << 2);
#pragma unroll
    for (int nt = 0; nt < 8; ++nt) {
      int n = nt * 16 + l15;
      *(b16x4*)(sAct + n * 1024 + ((o0 * 2) ^ SWZ(n))) = st[ot][nt];
    }
  }
  __syncthreads();  // writes visible
}

__global__ __launch_bounds__(512, 2) void fkan_inr_kernel(
    const float* __restrict__ coords, const float* __restrict__ fkan_bias,
    const float* __restrict__ ln_g, const float* __restrict__ ln_b,
    const float* __restrict__ b1, const float* __restrict__ b2,
    const float* __restrict__ b3, const float* __restrict__ b4,
    const float* __restrict__ wout, const float* __restrict__ bout,
    const __bf16* __restrict__ ws, float* __restrict__ out) {
  __shared__ __align__(16) unsigned char sAct[TILE * 1024];   // 128 KB
  __shared__ float sSum[TILE], sSqs[TILE];
  __shared__ float sOutF[TILE][4];

  const int tid = threadIdx.x;
  const int lane = tid & 63, wid = tid >> 6;
  const int l15 = lane & 15, lh = lane >> 4;
  const int base_n = blockIdx.x * TILE;

  // ---- F: fourier features -> sAct[n][k], k<384 ; zero stats + out acc
  if (tid < TILE) {
    sSum[tid] = 0.f; sSqs[tid] = 0.f;
    sOutF[tid][0] = 0.f; sOutF[tid][1] = 0.f; sOutF[tid][2] = 0.f; sOutF[tid][3] = 0.f;
  }
#pragma unroll
  for (int p = 0; p < 6; ++p) {
    int id = tid + p * 512;               // 0..3071 = (n, i, gchunk of 8)
    int n = id / 24, rem = id % 24, i = rem >> 3, g0 = (rem & 7) * 8;
    float c = coords[(base_n + n) * 3 + i];
    b16x8 cv, sv;
#pragma unroll
    for (int j = 0; j < 8; ++j) {
      float ang = c * (float)(g0 + j + 1);
      float s, co;
      fast_sincos(ang, &s, &co);
      cv[j] = (__bf16)co;
      sv[j] = (__bf16)s;
    }
    int kc = (i * GRIDW + g0) * 2;
    *(b16x8*)(sAct + n * 1024 + (kc ^ SWZ(n))) = cv;
    int ks2 = (192 + i * GRIDW + g0) * 2;
    *(b16x8*)(sAct + n * 1024 + (ks2 ^ SWZ(n))) = sv;
  }
  __syncthreads();

  // ---- GEMM1 (384 -> 256) + fkan_bias + LayerNorm, in place
  {
    f32x4 acc[2][8] = {};
    const int o_base = wid * 32;
    gemm_kloop<K1, 2>(sAct, ws + OFF_FC, lane, o_base, acc);
#pragma unroll
    for (int ot = 0; ot < 2; ++ot) {
      int o0 = o_base + ot * 16 + (lh << 2);
      f32x4 bia = *(const f32x4*)(fkan_bias + o0);
#pragma unroll
      for (int nt = 0; nt < 8; ++nt) acc[ot][nt] += bia;
    }
#pragma unroll
    for (int nt = 0; nt < 8; ++nt) {
      float s = 0.f, q = 0.f;
#pragma unroll
      for (int ot = 0; ot < 2; ++ot)
#pragma unroll
        for (int r = 0; r < 4; ++r) { float z = acc[ot][nt][r]; s += z; q += z * z; }
      s += __shfl_xor(s, 16); q += __shfl_xor(q, 16);
      s += __shfl_xor(s, 32); q += __shfl_xor(q, 32);
      if (lane < 16) {
        atomicAdd(&sSum[nt * 16 + lane], s);
        atomicAdd(&sSqs[nt * 16 + lane], q);
      }
    }
    __syncthreads();  // stats ready AND all feature reads done
#pragma unroll
    for (int nt = 0; nt < 8; ++nt) {
      int n = nt * 16 + l15;
      float mu = sSum[n] * (1.f / HID);
      float var = sSqs[n] * (1.f / HID) - mu * mu;
      float rs = rsqrtf(var + LN_EPS);
#pragma unroll
      for (int ot = 0; ot < 2; ++ot) {
        int o0 = o_base + ot * 16 + (lh << 2);
        f32x4 g4 = *(const f32x4*)(ln_g + o0);
        f32x4 bb = *(const f32x4*)(ln_b + o0);
        b16x4 h;
        h[0] = (__bf16)((acc[ot][nt][0] - mu) * rs * g4[0] + bb[0]);
        h[1] = (__bf16)((acc[ot][nt][1] - mu) * rs * g4[1] + bb[1]);
        h[2] = (__bf16)((acc[ot][nt][2] - mu) * rs * g4[2] + bb[2]);
        h[3] = (__bf16)((acc[ot][nt][3] - mu) * rs * g4[3] + bb[3]);
        *(b16x4*)(sAct + n * 1024 + ((o0 * 2) ^ SWZ(n))) = h;
      }
    }
    __syncthreads();
  }

  // ---- sine layers 1..3 (in place, stash-before-barrier)
  sine_layer_ip<HID>(sAct, ws + OFF_W1, b1, lane, wid);
  sine_layer_ip<H2>(sAct, ws + OFF_W2, b2, lane, wid);
  sine_layer_ip<H2>(sAct, ws + OFF_W3, b3, lane, wid);

  // ---- layer 4 (512 -> 1024) fused with output projection (1024 -> 3)
  {
#pragma unroll 1
    for (int pass = 0; pass < 2; ++pass) {
      f32x4 acc[4][8] = {};
      int o_base = pass * 512 + wid * 64;
      gemm_kloop<H2, 4>(sAct, ws + OFF_W4, lane, o_base, acc);
      float pj[8][3] = {};
#pragma unroll
      for (int ot = 0; ot < 4; ++ot) {
        int o0 = o_base + ot * 16 + (lh << 2);
        f32x4 bia = *(const f32x4*)(b4 + o0);
        f32x4 wo0 = *(const f32x4*)(wout + 0 * H4 + o0);
        f32x4 wo1 = *(const f32x4*)(wout + 1 * H4 + o0);
        f32x4 wo2 = *(const f32x4*)(wout + 2 * H4 + o0);
#pragma unroll
        for (int nt = 0; nt < 8; ++nt) {
          float a0 = actfn(acc[ot][nt][0] + bia[0]);
          float a1 = actfn(acc[ot][nt][1] + bia[1]);
          float a2 = actfn(acc[ot][nt][2] + bia[2]);
          float a3 = actfn(acc[ot][nt][3] + bia[3]);
          pj[nt][0] += a0 * wo0[0] + a1 * wo0[1] + a2 * wo0[2] + a3 * wo0[3];
          pj[nt][1] += a0 * wo1[0] + a1 * wo1[1] + a2 * wo1[2] + a3 * wo1[3];
          pj[nt][2] += a0 * wo2[0] + a1 * wo2[1] + a2 * wo2[2] + a3 * wo2[3];
        }
      }
#pragma unroll
      for (int nt = 0; nt < 8; ++nt)
#pragma unroll
        for (int j = 0; j < 3; ++j) {
          float r = pj[nt][j];
          r += __shfl_xor(r, 16);
          r += __shfl_xor(r, 32);
          if (lane < 16) atomicAdd(&sOutF[nt * 16 + lane][j], r);
        }
    }
    __syncthreads();
    if (tid < TILE * 3) {
      int n = tid / 3, j = tid % 3;
      out[(base_n + n) * 3 + j] = sOutF[n][j] + bout[j];
    }
  }
}

extern "C" void kernel_launch(void* const* d_in, const int* in_sizes, int n_in,
                              void* d_out, int out_size, void* d_ws, size_t ws_size,
                              hipStream_t stream) {
  const float* coords    = (const float*)d_in[0];
  const float* fc        = (const float*)d_in[1];
  const float* fkan_bias = (const float*)d_in[2];
  const float* ln_g      = (const float*)d_in[3];
  const float* ln_b      = (const float*)d_in[4];
  const float* w1        = (const float*)d_in[5];
  const float* b1        = (const float*)d_in[6];
  const float* w2        = (const float*)d_in[7];
  const float* b2        = (const float*)d_in[8];
  const float* w3        = (const float*)d_in[9];
  const float* b3        = (const float*)d_in[10];
  const float* w4        = (const float*)d_in[11];
  const float* b4        = (const float*)d_in[12];
  const float* wout      = (const float*)d_in[13];
  const float* bout      = (const float*)d_in[14];
  float* out = (float*)d_out;
  __bf16* ws = (__bf16*)d_ws;

  prep_kernel<<<(N_TOTAL + 255) / 256, 256, 0, stream>>>(fc, w1, w2, w3, w4, ws);
  fkan_inr_kernel<<<N_PTS / TILE, 512, 0, stream>>>(coords, fkan_bias, ln_g, ln_b,
                                                    b1, b2, b3, b4, wout, bout, ws, out);
}